// Round 9
// baseline (266.300 us; speedup 1.0000x reference)
//
#include <hip/hip_runtime.h>
#include <hip/hip_bf16.h>
#include <cstdint>
#include <cstddef>

// ThermodynamicAttention: q=xWq+bq, k=xWk+bk, v=xWv+bv (B=4,S=2048,D=1024)
// scores = q@k^T / 8 / temp; probs = softmax(scores); H = mean row entropy
// out0 = probs@v (fp32, 8388608 elems), out1 = H (1 elem)
//
// R9: MFMA shape 16x16x32 -> 32x32x16. Same FLOPs & LDS traffic per K-step
// but HALF the MFMA instructions at ~17% higher per-cycle matrix throughput
// (m119: 2495 vs 2176 TF). Wave = 2x2 tiles of 32x32 (64 acc VGPRs, as before).
// C/D layout (m74/m101-verified): col=lane&31, row=(reg&3)+8*(reg>>2)+4*(lane>>5).
// A/B frag (inferred from verified 16x16x32 pattern): m=lane&31, k=8*(lane>>5)+j.
//
// Workspace layout (bytes), ~104 MB:
//   0          qb    (bf16, 16MB)  [q pre-scaled by 1/(8*temp)]
//   16777216   kb    (bf16, 16MB)
//   33554432   vt    (bf16 v transposed [b][d][s], 16MB)
//   50331648   xb    (bf16 x, 16MB)
//   67108864   Wt    (bf16 [Wqt|Wkt|Wvt], 6MB)
//   73400320   Pt    (bf16 e^x, 4x2048x2048, 32MB)
//   106954752  stats (fp32 [8192][32][2], 2MB)
//   109051904  inv_l (fp32 [8192], 32KB)
//   109084672  Hrow  (fp32 [8192], 32KB)

typedef __attribute__((ext_vector_type(8))) short short8;
typedef __attribute__((ext_vector_type(4))) short short4v;
typedef __attribute__((ext_vector_type(16))) float f32x16;

#define GLOBAL_AS __attribute__((address_space(1)))
#define LDS_AS __attribute__((address_space(3)))

__device__ __forceinline__ void async_load16(const void* g, void* lds) {
  __builtin_amdgcn_global_load_lds((GLOBAL_AS void*)g, (LDS_AS void*)lds, 16, 0, 0);
}

__device__ __forceinline__ short f2bf_s(float x) {
  __hip_bfloat16 h = __float2bfloat16(x);
  return *reinterpret_cast<short*>(&h);
}

// ---------------------------------------------------------------------------
// bf16 "bt" GEMM body: C[M,N] = A[M,K] @ Bt[N,K]^T, 128x128 tile, BK=64,
// 256 threads = 4 waves in 2x2 (each wave 64x64 = 2x2 of 32x32x16 MFMA,
// 4 k-steps of 16 per K-iter: 16 ds_read_b128 + 16 MFMA).
// LDS (R8 layout): 128 rows x 64 cols bf16 = 16KB/operand; 16B chunk c holds
// global (row=c>>3, col-octet=(c&7)^(row&7)). Staging thread t pass p owns
// chunk t+256p. Read side: global octet kk*2+half lives at chunk col
// (kk*2+half)^(row&7) -> uniform 8 lanes/bank-group (minimal phases).
// MODE 1: bf16 C + bias, scaled by 1/(8*aux[0]) if aux (q) else 1 (k)
// MODE 2: bf16 transposed-v + bias   (vt[b][col][s], b=row>>11)
// MODE 3: P~ = bf16(e^acc) + per-(row,chunk64) stats (l = sum e, w = sum e*x)
// MODE 4: fp32 C scaled by aux[row]  (PV normalization)
// ---------------------------------------------------------------------------
template <int MODE>
__device__ __forceinline__
void gemm_body(const __hip_bfloat16* __restrict__ A,
               const __hip_bfloat16* __restrict__ Bt,
               void* __restrict__ Cout,
               const float* __restrict__ bias,
               int K, int lda, int ldb, int ldc,
               __hip_bfloat16* __restrict__ sA,
               __hip_bfloat16* __restrict__ sB,
               int m0, int n0,
               const float* __restrict__ aux,
               float* __restrict__ stats) {
  const int tid  = threadIdx.x;
  const int lane = tid & 63;
  const int wid  = tid >> 6;
  const int wm = (wid >> 1) * 64;
  const int wn = (wid & 1) * 64;
  const int l31  = lane & 31;
  const int half = lane >> 5;     // k-octet select (frags); +4 rows (C/D)
  const int rx   = l31 & 7;       // row&7 for all frag rows (wm, mi*32 = 0 mod 8)

  f32x16 acc[2][2] = {};          // [mi][ni], 64 VGPRs

  const int srow = tid >> 3;
  const int scol = ((tid & 7) ^ ((tid >> 3) & 7)) * 8;
  const __hip_bfloat16* Ag = A  + (size_t)(m0 + srow) * lda + scol;
  const __hip_bfloat16* Bg = Bt + (size_t)(n0 + srow) * ldb + scol;

  for (int k0 = 0; k0 < K; k0 += 64) {
#pragma unroll
    for (int p = 0; p < 4; ++p) {
      async_load16(Ag + k0 + (size_t)(32 * p) * lda, &sA[(wid * 64 + 256 * p) * 8]);
      async_load16(Bg + k0 + (size_t)(32 * p) * ldb, &sB[(wid * 64 + 256 * p) * 8]);
    }
    __syncthreads();

#pragma unroll
    for (int kk = 0; kk < 4; ++kk) {
      const int co = ((kk * 2 + half) ^ rx) * 8;
      short8 af[2], bf[2];
#pragma unroll
      for (int mi = 0; mi < 2; ++mi)
        af[mi] = *(const short8*)&sA[(wm + mi * 32 + l31) * 64 + co];
#pragma unroll
      for (int ni = 0; ni < 2; ++ni)
        bf[ni] = *(const short8*)&sB[(wn + ni * 32 + l31) * 64 + co];

#pragma unroll
      for (int mi = 0; mi < 2; ++mi)
#pragma unroll
        for (int ni = 0; ni < 2; ++ni)
          acc[mi][ni] = __builtin_amdgcn_mfma_f32_32x32x16_bf16(
              af[mi], bf[ni], acc[mi][ni], 0, 0, 0);
    }
    __syncthreads();
  }

  // Epilogues. C/D (m74/m101-verified): col = lane&31,
  // row = (reg&3) + 8*(reg>>2) + 4*half, reg in [0,16).
  if (MODE == 3) {
    const int chunk = (n0 + wn) >> 6;   // wn is 64 wide = one stats chunk
#pragma unroll
    for (int mi = 0; mi < 2; ++mi) {
#pragma unroll
      for (int g = 0; g < 4; ++g) {
        float lv[4] = {}, wv[4] = {};
#pragma unroll
        for (int ni = 0; ni < 2; ++ni)
#pragma unroll
          for (int r = 0; r < 4; ++r) {
            const float xv = acc[mi][ni][g * 4 + r];  // already /(8*temp)
            const float e = __expf(xv);
            acc[mi][ni][g * 4 + r] = e;
            lv[r] += e;
            wv[r] += e * xv;
          }
#pragma unroll
        for (int r = 0; r < 4; ++r) {
          float l = lv[r], w = wv[r];
#pragma unroll
          for (int off = 1; off < 32; off <<= 1) {  // within-half: all 32 lanes same row
            l += __shfl_xor(l, off);
            w += __shfl_xor(w, off);
          }
          if (l31 == 0) {
            const int row = m0 + wm + mi * 32 + g * 8 + 4 * half + r;
            *(float2*)&stats[((size_t)row * 32 + chunk) * 2] = make_float2(l, w);
          }
        }
      }
      // Pt store
#pragma unroll
      for (int ni = 0; ni < 2; ++ni) {
        const int col = n0 + wn + ni * 32 + l31;
#pragma unroll
        for (int g = 0; g < 4; ++g)
#pragma unroll
          for (int r = 0; r < 4; ++r) {
            const int row = m0 + wm + mi * 32 + g * 8 + 4 * half + r;
            ((__hip_bfloat16*)Cout)[(size_t)row * ldc + col] =
                __float2bfloat16(acc[mi][ni][g * 4 + r]);
          }
      }
    }
  } else if (MODE == 4) {
#pragma unroll
    for (int mi = 0; mi < 2; ++mi)
#pragma unroll
      for (int g = 0; g < 4; ++g)
#pragma unroll
        for (int r = 0; r < 4; ++r) {
          const int row = m0 + wm + mi * 32 + g * 8 + 4 * half + r;
          const float sc = aux[row];
#pragma unroll
          for (int ni = 0; ni < 2; ++ni) {
            const int col = n0 + wn + ni * 32 + l31;
            ((float*)Cout)[(size_t)row * ldc + col] = acc[mi][ni][g * 4 + r] * sc;
          }
        }
  } else {
    const float qsc = (MODE == 1 && aux) ? 1.0f / (8.0f * aux[0]) : 1.0f;
#pragma unroll
    for (int mi = 0; mi < 2; ++mi) {
#pragma unroll
      for (int ni = 0; ni < 2; ++ni) {
        const int col = n0 + wn + ni * 32 + l31;
        const float badd = bias[col];
        if (MODE == 2) {
#pragma unroll
          for (int g = 0; g < 4; ++g) {
            // rows g*8+4*half+{0..3} are consecutive -> short4 into vt
            const int rowb = m0 + wm + mi * 32 + g * 8 + 4 * half;
            short4v o;
#pragma unroll
            for (int r = 0; r < 4; ++r) o[r] = f2bf_s(acc[mi][ni][g * 4 + r] + badd);
            const size_t idx = (size_t)(rowb >> 11) * (1024u * 2048u) +
                               (size_t)col * 2048u + (size_t)(rowb & 2047);
            *(short4v*)((short*)Cout + idx) = o;
          }
        } else {
#pragma unroll
          for (int g = 0; g < 4; ++g)
#pragma unroll
            for (int r = 0; r < 4; ++r) {
              const int row = m0 + wm + mi * 32 + g * 8 + 4 * half + r;
              ((__hip_bfloat16*)Cout)[(size_t)row * ldc + col] =
                  __float2bfloat16((acc[mi][ni][g * 4 + r] + badd) * qsc);
            }
        }
      }
    }
  }
}

// --- XCD-swizzled wrappers (block lin -> XCD lin%8; groups congruent mod 8) --

// QKV: flat grid 1536. Group = 8 blocks (fixed y, all 8 x) sharing one A-strip.
__global__ __launch_bounds__(256)
void qkv_fused(const __hip_bfloat16* __restrict__ xb,
               const __hip_bfloat16* __restrict__ Wt,
               __hip_bfloat16* __restrict__ qb, __hip_bfloat16* __restrict__ kb,
               __hip_bfloat16* __restrict__ vt,
               const float* __restrict__ bq, const float* __restrict__ bk,
               const float* __restrict__ bv, const float* __restrict__ tptr) {
  __shared__ __align__(16) __hip_bfloat16 sA[128 * 64];
  __shared__ __align__(16) __hip_bfloat16 sB[128 * 64];
  const int lin = blockIdx.x;
  const int j = lin & 7, t = lin >> 3;
  const int x = t & 7;
  const int G = j + 8 * (t >> 3);
  const int z = G >> 6, y = G & 63;
  const int m0 = y * 128, n0 = x * 128;

  const __hip_bfloat16* B = Wt + (size_t)z * 1024 * 1024;
  if (z == 0)
    gemm_body<1>(xb, B, qb, bq, 1024, 1024, 1024, 1024, sA, sB, m0, n0, tptr, nullptr);
  else if (z == 1)
    gemm_body<1>(xb, B, kb, bk, 1024, 1024, 1024, 1024, sA, sB, m0, n0, nullptr, nullptr);
  else
    gemm_body<2>(xb, B, vt, bv, 1024, 1024, 1024, 0, sA, sB, m0, n0, nullptr, nullptr);
}

// Scores->P~: flat grid 1024. Group = 16 blocks (4y x 4x).
__global__ __launch_bounds__(256)
void scores_swz(const __hip_bfloat16* __restrict__ qb,
                const __hip_bfloat16* __restrict__ kb,
                __hip_bfloat16* __restrict__ Pt,
                float* __restrict__ stats) {
  __shared__ __align__(16) __hip_bfloat16 sA[128 * 64];
  __shared__ __align__(16) __hip_bfloat16 sB[128 * 64];
  const int lin = blockIdx.x;
  const int j = lin & 7, t = lin >> 3;
  const int w = t & 15;
  const int G = j + 8 * (t >> 4);
  const size_t z = G >> 4;
  const int r = G & 15;
  const int y = (r >> 2) * 4 + (w >> 2);
  const int x = (r & 3) * 4 + (w & 3);
  gemm_body<3>(qb + z * 2048 * 1024, kb + z * 2048 * 1024,
               Pt + z * 2048 * 2048, nullptr, 1024, 1024, 1024, 2048,
               sA, sB, y * 128, x * 128, nullptr, stats + z * 2048 * 64);
}

// PV: flat grid 512. Group = 4 blocks (2y x 2x). out scaled by inv_l[row].
__global__ __launch_bounds__(256)
void pv_swz(const __hip_bfloat16* __restrict__ Pt,
            const __hip_bfloat16* __restrict__ vt,
            float* __restrict__ out,
            const float* __restrict__ inv_l) {
  __shared__ __align__(16) __hip_bfloat16 sA[128 * 64];
  __shared__ __align__(16) __hip_bfloat16 sB[128 * 64];
  const int lin = blockIdx.x;
  const int j = lin & 7, t = lin >> 3;
  const int w = t & 3;
  const int G = j + 8 * (t >> 2);
  const size_t z = G >> 5;
  const int r = G & 31;
  const int y = (r >> 2) * 2 + (w >> 1);
  const int x = (r & 3) * 2 + (w & 1);
  gemm_body<4>(Pt + z * 2048 * 2048, vt + z * 1024 * 2048,
               out + z * 2048 * 1024, nullptr, 2048, 2048, 2048, 1024,
               sA, sB, y * 128, x * 128, inv_l + z * 2048, nullptr);
}

// ---------------------------------------------------------------------------
__global__ __launch_bounds__(256)
void cast_f32_to_bf16(const float* __restrict__ src,
                      __hip_bfloat16* __restrict__ dst, int n) {
  const int i = (blockIdx.x * 256 + threadIdx.x) * 8;
  if (i >= n) return;
  const float4 a = *(const float4*)(src + i);
  const float4 b = *(const float4*)(src + i + 4);
  short8 o;
  o[0] = f2bf_s(a.x); o[1] = f2bf_s(a.y); o[2] = f2bf_s(a.z); o[3] = f2bf_s(a.w);
  o[4] = f2bf_s(b.x); o[5] = f2bf_s(b.y); o[6] = f2bf_s(b.z); o[7] = f2bf_s(b.w);
  *(short8*)((short*)dst + i) = o;
}

// All three weight transposes in one dispatch: grid (16,16,3).
__global__ __launch_bounds__(256)
void transpose_cast_3w(const float* __restrict__ Wq, const float* __restrict__ Wk,
                       const float* __restrict__ Wv,
                       __hip_bfloat16* __restrict__ Wt) {
  __shared__ float tile[64][65];
  const int z = blockIdx.z;
  const float* src = (z == 0) ? Wq : (z == 1) ? Wk : Wv;
  __hip_bfloat16* dst = Wt + (size_t)z * 1024 * 1024;
  const int c0 = blockIdx.x * 64;
  const int r0 = blockIdx.y * 64;
  const int lane = threadIdx.x & 63;
  const int grp  = threadIdx.x >> 6;
#pragma unroll
  for (int i = 0; i < 16; ++i) {
    const int r = grp * 16 + i;
    tile[r][lane] = src[(size_t)(r0 + r) * 1024 + c0 + lane];
  }
  __syncthreads();
#pragma unroll
  for (int i = 0; i < 16; ++i) {
    const int r = grp * 16 + i;
    dst[(size_t)(c0 + r) * 1024 + r0 + lane] = __float2bfloat16(tile[lane][r]);
  }
}

// ---------------------------------------------------------------------------
// Per-row stats reduction: row's 32 (l,w) chunk-pairs (256B contiguous) ->
// inv_l[row] = 1/sum(l), Hrow[row] = log(l) - w/l. 8192 rows, 32 blocks.
__global__ __launch_bounds__(256)
void stats_reduce(const float* __restrict__ stats,
                  float* __restrict__ inv_l, float* __restrict__ Hrow) {
  const int row = blockIdx.x * 256 + threadIdx.x;
  const float* sp = stats + (size_t)row * 64;
  float l = 0.f, w = 0.f;
#pragma unroll
  for (int j = 0; j < 16; ++j) {
    const float4 a = *(const float4*)(sp + j * 4);
    l += a.x + a.z;
    w += a.y + a.w;
  }
  const float il = 1.0f / l;
  inv_l[row] = il;
  Hrow[row] = __logf(l) - w * il;
}

// One block: sum Hrow[0..8191], out = mean.
__global__ __launch_bounds__(256)
void reduce_entropy(const float* __restrict__ Hrow, float* __restrict__ out) {
  const int tid  = threadIdx.x;
  const int lane = tid & 63;
  const int wid  = tid >> 6;
  float s = 0.f;
#pragma unroll
  for (int j = 0; j < 8; ++j) {
    const float4 a = *(const float4*)(Hrow + j * 1024 + tid * 4);
    s += a.x + a.y + a.z + a.w;
  }
#pragma unroll
  for (int off = 1; off < 64; off <<= 1) s += __shfl_xor(s, off);
  __shared__ float red[4];
  if (lane == 0) red[wid] = s;
  __syncthreads();
  if (tid == 0)
    out[0] = (red[0] + red[1] + red[2] + red[3]) * (1.0f / 8192.0f);
}

// ---------------------------------------------------------------------------
extern "C" void kernel_launch(void* const* d_in, const int* in_sizes, int n_in,
                              void* d_out, int out_size, void* d_ws, size_t ws_size,
                              hipStream_t stream) {
  const float* x    = (const float*)d_in[0];
  const float* Wq   = (const float*)d_in[1];
  const float* bq   = (const float*)d_in[2];
  const float* Wk   = (const float*)d_in[3];
  const float* bk   = (const float*)d_in[4];
  const float* Wv   = (const float*)d_in[5];
  const float* bv   = (const float*)d_in[6];
  const float* temp = (const float*)d_in[7];
  float* out = (float*)d_out;
  char* ws = (char*)d_ws;

  __hip_bfloat16* qb    = (__hip_bfloat16*)(ws + 0);
  __hip_bfloat16* kb    = (__hip_bfloat16*)(ws + 16777216);
  __hip_bfloat16* vt    = (__hip_bfloat16*)(ws + 33554432);
  __hip_bfloat16* xb    = (__hip_bfloat16*)(ws + 50331648);
  __hip_bfloat16* Wt    = (__hip_bfloat16*)(ws + 67108864);
  __hip_bfloat16* Pt    = (__hip_bfloat16*)(ws + 73400320);
  float*          stats = (float*)(ws + 106954752);
  float*          inv_l = (float*)(ws + 109051904);
  float*          Hrow  = (float*)(ws + 109084672);

  cast_f32_to_bf16<<<4096, 256, 0, stream>>>(x, xb, 8388608);
  transpose_cast_3w<<<dim3(16, 16, 3), 256, 0, stream>>>(Wq, Wk, Wv, Wt);

  qkv_fused<<<1536, 256, 0, stream>>>(xb, Wt, qb, kb, vt, bq, bk, bv, temp);

  scores_swz<<<1024, 256, 0, stream>>>(qb, kb, Pt, stats);
  stats_reduce<<<32, 256, 0, stream>>>(stats, inv_l, Hrow);
  pv_swz<<<512, 256, 0, stream>>>(Pt, vt, out, inv_l);

  reduce_entropy<<<1, 256, 0, stream>>>(Hrow, out + 8388608);
}